// Round 9
// baseline (174.786 us; speedup 1.0000x reference)
//
#include <hip/hip_runtime.h>
#include <hip/hip_bf16.h>

#define N_NODES 32768
#define DEG 16
#define E_EDGES (N_NODES * DEG)
#define HEADS 4
#define OUT_D 64
#define HD 256            // HEADS*OUT_D
#define SLOPE 0.2f
#define GMARG 0.1f
#define CMARG 0.1f
#define LOSS_BLOCKS 2048   // N_NODES/16

typedef float f32x4 __attribute__((ext_vector_type(4)));
typedef int   int4v __attribute__((ext_vector_type(4)));
typedef unsigned short ushort4v __attribute__((ext_vector_type(4)));
typedef unsigned short ushort8v __attribute__((ext_vector_type(8)));
typedef short bf16x8 __attribute__((ext_vector_type(8)));
typedef short short4v __attribute__((ext_vector_type(4)));

__device__ __forceinline__ float bf2f(unsigned short u) {
    return __uint_as_float(((unsigned int)u) << 16);
}
__device__ __forceinline__ unsigned short f2bf(float x) {
    __hip_bfloat16 h = __float2bfloat16(x);   // RNE
    return __builtin_bit_cast(unsigned short, h);
}
__device__ __forceinline__ short f2bf_s(float x) {
    __hip_bfloat16 h = __float2bfloat16(x);
    return __builtin_bit_cast(short, h);
}
__device__ __forceinline__ float leaky(float x) {
    return x >= 0.f ? x : SLOPE * x;
}
__device__ __forceinline__ void gl_lds16(const void* g, void* l) {
    __builtin_amdgcn_global_load_lds(
        (__attribute__((address_space(1))) void*)(g),
        (__attribute__((address_space(3))) void*)(l), 16, 0, 0);
}

__global__ void badcfg_kernel(float* out, float code) {
    out[0] = code;
}

// ---------------------------------------------------------------------------
// K0: convert W [256,256] fp32 -> bf16 (into ws)
// ---------------------------------------------------------------------------
__global__ __launch_bounds__(256) void convw_kernel(const float* __restrict__ W,
                                                    short* __restrict__ Wb) {
    const int i = (blockIdx.x * 256 + threadIdx.x) * 4;
    f32x4 v = *(const f32x4*)(W + i);
    short4v o;
    o[0] = f2bf_s(v[0]); o[1] = f2bf_s(v[1]); o[2] = f2bf_s(v[2]); o[3] = f2bf_s(v[3]);
    *(short4v*)(Wb + i) = o;
}

// ---------------------------------------------------------------------------
// K1 (R8-proven, byte-identical): fs = feat @ W^T via MFMA 16x16x32 bf16.
// ---------------------------------------------------------------------------
__global__ __launch_bounds__(256) void gemm_kernel(const float* __restrict__ feat,
                                                   const short* __restrict__ Wb,
                                                   const float* __restrict__ attn_l,
                                                   const float* __restrict__ attn_r,
                                                   unsigned short* __restrict__ fsb,
                                                   float* __restrict__ el,
                                                   float* __restrict__ er) {
    __shared__ short s_b[2][16384];   // 2 x 32KB double buffer (exactly 64KB)

    const int tid = threadIdx.x;
    const int wave = tid >> 6;
    const int lane = tid & 63;
    const int row0 = (blockIdx.x * 4 + wave) * 16;
    const int m = lane & 15;
    const int q = lane >> 4;

    // ---- issue chunk-0 staging first so DMA overlaps afr load+cvt ----
#pragma unroll
    for (int i = 0; i < 8; ++i) {
        const int sb = wave * 8 + i;
        const int kk2 = sb >> 4, t = sb & 15;
        const short* g = Wb + (size_t)(t * 16 + m) * HD + kk2 * 32 + q * 8;
        gl_lds16(g, &s_b[0][sb * 512]);
    }

    // ---- A fragments: afr[kk] = A[row=m][k = kk*32 + q*8 .. +8] ----
    bf16x8 afr[8];
    const float* arow = feat + (size_t)(row0 + m) * HD + q * 8;
#pragma unroll
    for (int kk = 0; kk < 8; ++kk) {
        f32x4 lo = *(const f32x4*)(arow + kk * 32);
        f32x4 hi = *(const f32x4*)(arow + kk * 32 + 4);
        bf16x8 aa;
        aa[0] = f2bf_s(lo[0]); aa[1] = f2bf_s(lo[1]); aa[2] = f2bf_s(lo[2]); aa[3] = f2bf_s(lo[3]);
        aa[4] = f2bf_s(hi[0]); aa[5] = f2bf_s(hi[1]); aa[6] = f2bf_s(hi[2]); aa[7] = f2bf_s(hi[3]);
        afr[kk] = aa;
    }

    f32x4 acc[16];
#pragma unroll
    for (int t = 0; t < 16; ++t) acc[t] = (f32x4)(0.0f);

    __syncthreads();   // vmcnt(0) drain + barrier: chunk 0 resident

#pragma unroll
    for (int c = 0; c < 4; ++c) {
        if (c < 3) {   // prefetch chunk c+1 into the buffer read at iter c-1
#pragma unroll
            for (int i = 0; i < 8; ++i) {
                const int sb = wave * 8 + i;
                const int kk2 = sb >> 4, t = sb & 15;
                const short* g = Wb + (size_t)(t * 16 + m) * HD + (c + 1) * 64 + kk2 * 32 + q * 8;
                gl_lds16(g, &s_b[(c + 1) & 1][sb * 512]);
            }
        }
        const short* sbc = s_b[c & 1];
#pragma unroll
        for (int kk2 = 0; kk2 < 2; ++kk2) {
            const bf16x8 af = afr[c * 2 + kk2];
#pragma unroll
            for (int t = 0; t < 16; ++t) {
                bf16x8 bfr = *(const bf16x8*)(sbc + ((kk2 * 16 + t) * 64 + lane) * 8);
                acc[t] = __builtin_amdgcn_mfma_f32_16x16x32_bf16(af, bfr, acc[t], 0, 0, 0);
            }
        }
        __syncthreads();   // drains prefetch vmcnt + protects buffer reuse
    }

    // ---- fsb store (C layout: row = q*4+r, col = t*16+m) ----
#pragma unroll
    for (int t = 0; t < 16; ++t) {
#pragma unroll
        for (int r = 0; r < 4; ++r) {
            fsb[(size_t)(row0 + q * 4 + r) * HD + t * 16 + m] = f2bf(acc[t][r]);
        }
    }

    // ---- fused el/er epilogue: head h = t>>2; reduce over m-lanes ----
    float pel[4][4], per_[4][4];
#pragma unroll
    for (int h = 0; h < 4; ++h)
#pragma unroll
        for (int r = 0; r < 4; ++r) { pel[h][r] = 0.f; per_[h][r] = 0.f; }
#pragma unroll
    for (int t = 0; t < 16; ++t) {
        const float al = attn_l[t * 16 + m];
        const float ar = attn_r[t * 16 + m];
        const int h = t >> 2;
#pragma unroll
        for (int r = 0; r < 4; ++r) {
            pel[h][r] += acc[t][r] * al;
            per_[h][r] += acc[t][r] * ar;
        }
    }
#pragma unroll
    for (int mask = 1; mask < 16; mask <<= 1) {
#pragma unroll
        for (int h = 0; h < 4; ++h)
#pragma unroll
            for (int r = 0; r < 4; ++r) {
                pel[h][r] += __shfl_xor(pel[h][r], mask, 64);
                per_[h][r] += __shfl_xor(per_[h][r], mask, 64);
            }
    }
    if (m == 0) {
#pragma unroll
        for (int r = 0; r < 4; ++r) {
            const int node = row0 + q * 4 + r;
            f32x4 vl, vr;
            vl[0] = pel[0][r]; vl[1] = pel[1][r]; vl[2] = pel[2][r]; vl[3] = pel[3][r];
            vr[0] = per_[0][r]; vr[1] = per_[1][r]; vr[2] = per_[2][r]; vr[3] = per_[3][r];
            *(f32x4*)(el + (size_t)node * 4) = vl;
            *(f32x4*)(er + (size_t)node * 4) = vr;
        }
    }
}

// ---------------------------------------------------------------------------
// K2 (R4-proven): Lg/Lb partials + SOFTMAX WEIGHTS (computed once -> aww).
// lane = edge (4 heads in-lane), 16 nodes/block. Analytic dst: nd=perm[e]>>4.
// aww layout: [n][h][a] fp32 -> 64B contiguous per (n,h).
// ---------------------------------------------------------------------------
__global__ __launch_bounds__(256) void loss_kernel(const int* __restrict__ src,
                                                   const int* __restrict__ perm,
                                                   const int* __restrict__ label,
                                                   const float* __restrict__ el,
                                                   const float* __restrict__ er,
                                                   float* __restrict__ aww,
                                                   float* __restrict__ partials) {
    __shared__ float s_pw[16][16][4];   // [node_local][a][h]  (4 KB)
    __shared__ int   s_adj[16][16];
    __shared__ float slg[4], slb[4];

    const int tid = threadIdx.x;
    const int wave = tid >> 6;
    const int lane = tid & 63;
    const int w = lane >> 4;
    const int a = lane & 15;
    const int nl = wave * 4 + w;
    const int n = blockIdx.x * 16 + nl;
    const int e = n * DEG + a;

    const int s  = src[e];
    const int nd = perm[e] >> 4;        // dst[perm[e]] == perm[e]>>4 (HW-verified)
    f32x4 els  = *(const f32x4*)(el + (size_t)s * 4);
    f32x4 ern  = *(const f32x4*)(er + (size_t)n * 4);
    f32x4 ernd = *(const f32x4*)(er + (size_t)nd * 4);
    const int adja = (label[s] == label[n]) ? 1 : 0;

    f32x4 pw, nw;
#pragma unroll
    for (int h = 0; h < 4; ++h) {
        pw[h] = leaky(els[h] + ern[h]);
        nw[h] = leaky(els[h] + ernd[h]);
    }
    *(f32x4*)&s_pw[nl][a][0] = pw;
    s_adj[nl][a] = adja;

    // ---- softmax over the 16 edges of this node (masks <16 stay in group) ----
    {
        f32x4 mx = pw;
#pragma unroll
        for (int mask = 1; mask < 16; mask <<= 1)
#pragma unroll
            for (int h = 0; h < 4; ++h)
                mx[h] = fmaxf(mx[h], __shfl_xor(mx[h], mask, 64));
        f32x4 ee, sm;
#pragma unroll
        for (int h = 0; h < 4; ++h) { ee[h] = __expf(pw[h] - mx[h]); sm[h] = ee[h]; }
#pragma unroll
        for (int mask = 1; mask < 16; mask <<= 1)
#pragma unroll
            for (int h = 0; h < 4; ++h)
                sm[h] += __shfl_xor(sm[h], mask, 64);
#pragma unroll
        for (int h = 0; h < 4; ++h)
            aww[(((size_t)n * 4 + h) << 4) + a] = ee[h] / sm[h];
    }
    __syncthreads();

    float lg = 0.f, lb = 0.f;
#pragma unroll
    for (int b = 0; b < 16; ++b) {
        f32x4 pwb = *(const f32x4*)&s_pw[nl][b][0];   // broadcast within node
        const int adjb = s_adj[nl][b];
#pragma unroll
        for (int h = 0; h < 4; ++h)
            lg += fmaxf(nw[h] + GMARG - pwb[h], 0.f);
        if (adja && !adjb) {
#pragma unroll
            for (int h = 0; h < 4; ++h)
                lb += fmaxf(pwb[h] + CMARG - pw[h], 0.f);
        }
    }
#pragma unroll
    for (int mask = 1; mask < 64; mask <<= 1) {
        lg += __shfl_xor(lg, mask, 64);
        lb += __shfl_xor(lb, mask, 64);
    }
    if (lane == 0) { slg[wave] = lg; slb[wave] = lb; }
    __syncthreads();
    if (tid == 0) {
        partials[blockIdx.x * 2]     = slg[0] + slg[1] + slg[2] + slg[3];
        partials[blockIdx.x * 2 + 1] = slb[0] + slb[1] + slb[2] + slb[3];
    }
}

// ---------------------------------------------------------------------------
// K3: XCD-SLICED aggregate, v3. Grid 2048: cg = blk&7 = 32-ch slice == XCD
// (round-robin dispatch) -> per-XCD fsb gather working set = 2.1 MB slice,
// L2-resident. Block = 128 nodes.
// Phase A: COALESCED loads of src + precomputed aww (int4/f32x4, 64B/thread,
//   normal cached loads — NOT the R3 scalar recompute, NOT the R4 NT loads)
//   staged to LDS [j][node].
// Phase B: R3's proven 24-VGPR gather loop (unroll 4, no reg batching).
// Normal stores (R4's NT stores inflated WRITE_SIZE).
// ---------------------------------------------------------------------------
__global__ __launch_bounds__(256) void agg_kernel(const int* __restrict__ src,
                                                  const float* __restrict__ aww,
                                                  const unsigned short* __restrict__ fsb,
                                                  float* __restrict__ out) {
    __shared__ float s_a[16][128];   // [j][node_local]
    __shared__ int   s_s[16][128];

    const int tid = threadIdx.x;
    const int cg = blockIdx.x & 7;      // slice == XCD (dispatch round-robin)
    const int ng = blockIdx.x >> 3;     // 256 node-groups of 128 nodes
    const int hh = cg >> 1;             // head of this 32-ch slice

    // ---- phase A: thread -> (nl = tid>>1, j0 = (tid&1)*8); coalesced ----
    {
        const int nl = tid >> 1;
        const int j0 = (tid & 1) * 8;
        const int n = ng * 128 + nl;
        int4v sa = *(const int4v*)(src + n * DEG + j0);
        int4v sb = *(const int4v*)(src + n * DEG + j0 + 4);
        const float* ap = aww + (((size_t)n * 4 + hh) << 4) + j0;
        f32x4 aa = *(const f32x4*)(ap);
        f32x4 ab = *(const f32x4*)(ap + 4);
#pragma unroll
        for (int k = 0; k < 4; ++k) {
            s_s[j0 + k][nl]     = sa[k];
            s_s[j0 + 4 + k][nl] = sb[k];
            s_a[j0 + k][nl]     = aa[k];
            s_a[j0 + 4 + k][nl] = ab[k];
        }
    }
    __syncthreads();

    // ---- phase B (R3-proven): thread -> (nl2 = tid>>1, half = tid&1) ----
    const int nl2 = tid >> 1;
    const int half = tid & 1;
    const int n2 = ng * 128 + nl2;
    const int chb = cg * 32 + half * 16;

    float acc[16];
#pragma unroll
    for (int k = 0; k < 16; ++k) acc[k] = 0.f;
#pragma unroll 4
    for (int j = 0; j < 16; ++j) {
        const int s2 = s_s[j][nl2];
        const float awj = s_a[j][nl2];
        const unsigned short* rp = fsb + (size_t)s2 * HD + chb;
        ushort8v u0 = *(const ushort8v*)(rp);
        ushort8v u1 = *(const ushort8v*)(rp + 8);
#pragma unroll
        for (int k = 0; k < 8; ++k) acc[k]     += awj * bf2f(u0[k]);
#pragma unroll
        for (int k = 0; k < 8; ++k) acc[8 + k] += awj * bf2f(u1[k]);
    }
    float* op = out + (size_t)n2 * HD + chb;
#pragma unroll
    for (int i = 0; i < 4; ++i) {
        f32x4 v;
        v[0] = acc[i * 4]; v[1] = acc[i * 4 + 1]; v[2] = acc[i * 4 + 2]; v[3] = acc[i * 4 + 3];
        *(f32x4*)(op + i * 4) = v;
    }
}

// ---------------------------------------------------------------------------
// K4: reduce partials -> Lg, Lb (fp32 scalars; double accumulation)
// ---------------------------------------------------------------------------
__global__ __launch_bounds__(256) void finalize_kernel(const float* __restrict__ partials,
                                                       float* __restrict__ out) {
    const int tid = threadIdx.x;
    const int lane = tid & 63;
    const int wave = tid >> 6;
    double lg = 0.0, lb = 0.0;
    for (int i = tid; i < LOSS_BLOCKS; i += 256) {
        lg += (double)partials[i * 2];
        lb += (double)partials[i * 2 + 1];
    }
#pragma unroll
    for (int mask = 1; mask < 64; mask <<= 1) {
        lg += __shfl_xor(lg, mask, 64);
        lb += __shfl_xor(lb, mask, 64);
    }
    __shared__ double slg[4], slb[4];
    if (lane == 0) { slg[wave] = lg; slb[wave] = lb; }
    __syncthreads();
    if (tid == 0) {
        const double scale = 1.0 / (double)((size_t)N_NODES * HEADS);
        out[(size_t)N_NODES * HD]     = (float)((slg[0] + slg[1] + slg[2] + slg[3]) * scale);
        out[(size_t)N_NODES * HD + 1] = (float)((slb[0] + slb[1] + slb[2] + slb[3]) * scale);
    }
}

extern "C" void kernel_launch(void* const* d_in, const int* in_sizes, int n_in,
                              void* d_out, int out_size, void* d_ws, size_t ws_size,
                              hipStream_t stream) {
    const float* feat   = (const float*)d_in[0];
    const int*   label  = (const int*)d_in[1];
    const int*   src    = (const int*)d_in[2];
    const int*   perm   = (const int*)d_in[4];
    const float* W      = (const float*)d_in[5];
    const float* attn_l = (const float*)d_in[6];
    const float* attn_r = (const float*)d_in[7];
    float* out = (float*)d_out;   // FP32 output

    const int expect[8] = {8388608, 32768, 524288, 524288, 524288, 65536, 256, 256};
    if (n_in != 8) {
        hipLaunchKernelGGL(badcfg_kernel, dim3(1), dim3(1), 0, stream, out, 60000.f);
        return;
    }
    for (int i = 0; i < 8; ++i) {
        if (in_sizes[i] != expect[i]) {
            hipLaunchKernelGGL(badcfg_kernel, dim3(1), dim3(1), 0, stream, out,
                               65536.f + 256.f * (float)i);
            return;
        }
    }
    if (out_size != N_NODES * HD + 2) {
        hipLaunchKernelGGL(badcfg_kernel, dim3(1), dim3(1), 0, stream, out, 200000.f);
        return;
    }

    char* ws = (char*)d_ws;
    size_t off = 0;
    float* partials = (float*)(ws + off); off += (size_t)LOSS_BLOCKS * 2 * sizeof(float);
    off = (off + 255) & ~(size_t)255;
    short* Wb = (short*)(ws + off); off += (size_t)HD * HD * sizeof(short);
    off = (off + 255) & ~(size_t)255;
    unsigned short* fsb = (unsigned short*)(ws + off); off += (size_t)N_NODES * HD * sizeof(unsigned short);
    float* el = (float*)(ws + off); off += (size_t)N_NODES * HEADS * sizeof(float);
    float* er = (float*)(ws + off); off += (size_t)N_NODES * HEADS * sizeof(float);
    off = (off + 255) & ~(size_t)255;
    float* aww = (float*)(ws + off); off += (size_t)N_NODES * HEADS * DEG * sizeof(float);
    if (off > ws_size) {
        hipLaunchKernelGGL(badcfg_kernel, dim3(1), dim3(1), 0, stream, out, 131072.f);
        return;
    }

    hipLaunchKernelGGL(convw_kernel, dim3(HD * HD / 1024), dim3(256), 0, stream, W, Wb);
    hipLaunchKernelGGL(gemm_kernel, dim3(N_NODES / 64), dim3(256), 0, stream,
                       feat, Wb, attn_l, attn_r, fsb, el, er);
    hipLaunchKernelGGL(loss_kernel, dim3(LOSS_BLOCKS), dim3(256), 0, stream,
                       src, perm, label, el, er, aww, partials);
    hipLaunchKernelGGL(agg_kernel, dim3(2048), dim3(256), 0, stream,
                       src, aww, fsb, out);
    hipLaunchKernelGGL(finalize_kernel, dim3(1), dim3(256), 0, stream, partials, out);
}

// Round 10
// 156.530 us; speedup vs baseline: 1.1166x; 1.1166x over previous
//
#include <hip/hip_runtime.h>
#include <hip/hip_bf16.h>

#define N_NODES 32768
#define DEG 16
#define E_EDGES (N_NODES * DEG)
#define HEADS 4
#define OUT_D 64
#define HD 256            // HEADS*OUT_D
#define SLOPE 0.2f
#define GMARG 0.1f
#define CMARG 0.1f
#define LOSS_BLOCKS 2048   // N_NODES/16

typedef float f32x4 __attribute__((ext_vector_type(4)));
typedef unsigned short ushort4v __attribute__((ext_vector_type(4)));
typedef unsigned short ushort8v __attribute__((ext_vector_type(8)));
typedef short bf16x8 __attribute__((ext_vector_type(8)));
typedef short short4v __attribute__((ext_vector_type(4)));

__device__ __forceinline__ float bf2f(unsigned short u) {
    return __uint_as_float(((unsigned int)u) << 16);
}
__device__ __forceinline__ unsigned short f2bf(float x) {
    __hip_bfloat16 h = __float2bfloat16(x);   // RNE
    return __builtin_bit_cast(unsigned short, h);
}
__device__ __forceinline__ short f2bf_s(float x) {
    __hip_bfloat16 h = __float2bfloat16(x);
    return __builtin_bit_cast(short, h);
}
__device__ __forceinline__ float leaky(float x) {
    return x >= 0.f ? x : SLOPE * x;
}
__device__ __forceinline__ void gl_lds16(const void* g, void* l) {
    __builtin_amdgcn_global_load_lds(
        (__attribute__((address_space(1))) void*)(g),
        (__attribute__((address_space(3))) void*)(l), 16, 0, 0);
}

__global__ void badcfg_kernel(float* out, float code) {
    out[0] = code;
}

// ---------------------------------------------------------------------------
// K0: convert W [256,256] fp32 -> bf16 (into ws)
// ---------------------------------------------------------------------------
__global__ __launch_bounds__(256) void convw_kernel(const float* __restrict__ W,
                                                    short* __restrict__ Wb) {
    const int i = (blockIdx.x * 256 + threadIdx.x) * 4;
    f32x4 v = *(const f32x4*)(W + i);
    short4v o;
    o[0] = f2bf_s(v[0]); o[1] = f2bf_s(v[1]); o[2] = f2bf_s(v[2]); o[3] = f2bf_s(v[3]);
    *(short4v*)(Wb + i) = o;
}

// ---------------------------------------------------------------------------
// K1 (R8-proven): fs = feat @ W^T via MFMA 16x16x32 bf16, merged col-halves.
// Grid = 512 node-tiles. Block: 64 nodes x 256 cols, 4 waves (16 rows/wave).
// feat read ONCE; Wb staged via global_load_lds (16B) into 2x32KB dbuf;
// fused el/er epilogue (all 4 heads in-block, constant-indexed stores).
// ---------------------------------------------------------------------------
__global__ __launch_bounds__(256) void gemm_kernel(const float* __restrict__ feat,
                                                   const short* __restrict__ Wb,
                                                   const float* __restrict__ attn_l,
                                                   const float* __restrict__ attn_r,
                                                   unsigned short* __restrict__ fsb,
                                                   float* __restrict__ el,
                                                   float* __restrict__ er) {
    __shared__ short s_b[2][16384];   // 2 x 32KB double buffer (exactly 64KB)

    const int tid = threadIdx.x;
    const int wave = tid >> 6;
    const int lane = tid & 63;
    const int row0 = (blockIdx.x * 4 + wave) * 16;
    const int m = lane & 15;
    const int q = lane >> 4;

    // ---- issue chunk-0 staging first so DMA overlaps afr load+cvt ----
#pragma unroll
    for (int i = 0; i < 8; ++i) {
        const int sb = wave * 8 + i;
        const int kk2 = sb >> 4, t = sb & 15;
        const short* g = Wb + (size_t)(t * 16 + m) * HD + kk2 * 32 + q * 8;
        gl_lds16(g, &s_b[0][sb * 512]);
    }

    // ---- A fragments: afr[kk] = A[row=m][k = kk*32 + q*8 .. +8] ----
    bf16x8 afr[8];
    const float* arow = feat + (size_t)(row0 + m) * HD + q * 8;
#pragma unroll
    for (int kk = 0; kk < 8; ++kk) {
        f32x4 lo = *(const f32x4*)(arow + kk * 32);
        f32x4 hi = *(const f32x4*)(arow + kk * 32 + 4);
        bf16x8 aa;
        aa[0] = f2bf_s(lo[0]); aa[1] = f2bf_s(lo[1]); aa[2] = f2bf_s(lo[2]); aa[3] = f2bf_s(lo[3]);
        aa[4] = f2bf_s(hi[0]); aa[5] = f2bf_s(hi[1]); aa[6] = f2bf_s(hi[2]); aa[7] = f2bf_s(hi[3]);
        afr[kk] = aa;
    }

    f32x4 acc[16];
#pragma unroll
    for (int t = 0; t < 16; ++t) acc[t] = (f32x4)(0.0f);

    __syncthreads();   // vmcnt(0) drain + barrier: chunk 0 resident

#pragma unroll
    for (int c = 0; c < 4; ++c) {
        if (c < 3) {   // prefetch chunk c+1 into the buffer read at iter c-1
#pragma unroll
            for (int i = 0; i < 8; ++i) {
                const int sb = wave * 8 + i;
                const int kk2 = sb >> 4, t = sb & 15;
                const short* g = Wb + (size_t)(t * 16 + m) * HD + (c + 1) * 64 + kk2 * 32 + q * 8;
                gl_lds16(g, &s_b[(c + 1) & 1][sb * 512]);
            }
        }
        const short* sbc = s_b[c & 1];
#pragma unroll
        for (int kk2 = 0; kk2 < 2; ++kk2) {
            const bf16x8 af = afr[c * 2 + kk2];
#pragma unroll
            for (int t = 0; t < 16; ++t) {
                bf16x8 bfr = *(const bf16x8*)(sbc + ((kk2 * 16 + t) * 64 + lane) * 8);
                acc[t] = __builtin_amdgcn_mfma_f32_16x16x32_bf16(af, bfr, acc[t], 0, 0, 0);
            }
        }
        __syncthreads();   // drains prefetch vmcnt + protects buffer reuse
    }

    // ---- fsb store (C layout: row = q*4+r, col = t*16+m) ----
#pragma unroll
    for (int t = 0; t < 16; ++t) {
#pragma unroll
        for (int r = 0; r < 4; ++r) {
            fsb[(size_t)(row0 + q * 4 + r) * HD + t * 16 + m] = f2bf(acc[t][r]);
        }
    }

    // ---- fused el/er epilogue: head h = t>>2; reduce over m-lanes ----
    float pel[4][4], per_[4][4];
#pragma unroll
    for (int h = 0; h < 4; ++h)
#pragma unroll
        for (int r = 0; r < 4; ++r) { pel[h][r] = 0.f; per_[h][r] = 0.f; }
#pragma unroll
    for (int t = 0; t < 16; ++t) {
        const float al = attn_l[t * 16 + m];
        const float ar = attn_r[t * 16 + m];
        const int h = t >> 2;
#pragma unroll
        for (int r = 0; r < 4; ++r) {
            pel[h][r] += acc[t][r] * al;
            per_[h][r] += acc[t][r] * ar;
        }
    }
#pragma unroll
    for (int mask = 1; mask < 16; mask <<= 1) {
#pragma unroll
        for (int h = 0; h < 4; ++h)
#pragma unroll
            for (int r = 0; r < 4; ++r) {
                pel[h][r] += __shfl_xor(pel[h][r], mask, 64);
                per_[h][r] += __shfl_xor(per_[h][r], mask, 64);
            }
    }
    if (m == 0) {   // lanes q*16: own rows q*4 + r, constant-indexed f32x4 stores
#pragma unroll
        for (int r = 0; r < 4; ++r) {
            const int node = row0 + q * 4 + r;
            f32x4 vl, vr;
            vl[0] = pel[0][r]; vl[1] = pel[1][r]; vl[2] = pel[2][r]; vl[3] = pel[3][r];
            vr[0] = per_[0][r]; vr[1] = per_[1][r]; vr[2] = per_[2][r]; vr[3] = per_[3][r];
            *(f32x4*)(el + (size_t)node * 4) = vl;
            *(f32x4*)(er + (size_t)node * 4) = vr;
        }
    }
}

// ---------------------------------------------------------------------------
// K2 (R8-proven, 48-VGPR version): FUSED loss + softmax + aggregate.
// 16 nodes/block, grid 2048.
// Phase A (lane = (node_local, edge), 4 heads in-lane): pw/nw/adj, Lg/Lb
//   partials, softmax weights -> LDS (all padded [16][17]).
// Phase B (thread = (node_local, 16-ch group)): gather fsb rows under
//   #pragma unroll 4 (NO register batching — keeps VGPR at 48, occupancy
//   ~37%; the R2-style 8-deep preload crosses the 64-VGPR cliff and
//   regresses to 57 µs / 142 MB FETCH).
// ---------------------------------------------------------------------------
__global__ __launch_bounds__(256) void fla_kernel(const int* __restrict__ src,
                                                  const int* __restrict__ perm,
                                                  const int* __restrict__ label,
                                                  const float* __restrict__ el,
                                                  const float* __restrict__ er,
                                                  const unsigned short* __restrict__ fsb,
                                                  float* __restrict__ out,
                                                  float* __restrict__ partials) {
    __shared__ float s_pw[16][17][4];   // padded: stride 68 words
    __shared__ float s_a[16][17][4];
    __shared__ int   s_adj[16][17];
    __shared__ int   s_srcn[16][17];
    __shared__ float slg[4], slb[4];

    const int tid = threadIdx.x;
    const int wave = tid >> 6;
    const int lane = tid & 63;
    const int w = lane >> 4;
    const int a = lane & 15;
    const int nl = wave * 4 + w;
    const int n = blockIdx.x * 16 + nl;
    const int e = n * DEG + a;

    const int s  = src[e];
    const int nd = perm[e] >> 4;        // dst[perm[e]] == perm[e]>>4 (HW-verified)
    f32x4 els  = *(const f32x4*)(el + (size_t)s * 4);
    f32x4 ern  = *(const f32x4*)(er + (size_t)n * 4);
    f32x4 ernd = *(const f32x4*)(er + (size_t)nd * 4);
    const int adja = (label[s] == label[n]) ? 1 : 0;

    f32x4 pw, nw;
#pragma unroll
    for (int h = 0; h < 4; ++h) {
        pw[h] = leaky(els[h] + ern[h]);
        nw[h] = leaky(els[h] + ernd[h]);
    }
    *(f32x4*)&s_pw[nl][a][0] = pw;
    s_adj[nl][a] = adja;
    s_srcn[nl][a] = s;

    // softmax over the 16 edges of this node (masks < 16 stay in the a-group)
    f32x4 mx = pw;
#pragma unroll
    for (int mask = 1; mask < 16; mask <<= 1)
#pragma unroll
        for (int h = 0; h < 4; ++h)
            mx[h] = fmaxf(mx[h], __shfl_xor(mx[h], mask, 64));
    f32x4 ee, sm;
#pragma unroll
    for (int h = 0; h < 4; ++h) { ee[h] = __expf(pw[h] - mx[h]); sm[h] = ee[h]; }
#pragma unroll
    for (int mask = 1; mask < 16; mask <<= 1)
#pragma unroll
        for (int h = 0; h < 4; ++h)
            sm[h] += __shfl_xor(sm[h], mask, 64);
    f32x4 aw;
#pragma unroll
    for (int h = 0; h < 4; ++h) aw[h] = ee[h] / sm[h];
    *(f32x4*)&s_a[nl][a][0] = aw;
    __syncthreads();

    // ---- losses (same math/order as verified loss_kernel) ----
    float lg = 0.f, lb = 0.f;
#pragma unroll
    for (int b = 0; b < 16; ++b) {
        f32x4 pwb = *(const f32x4*)&s_pw[nl][b][0];   // broadcast within node
        const int adjb = s_adj[nl][b];
#pragma unroll
        for (int h = 0; h < 4; ++h)
            lg += fmaxf(nw[h] + GMARG - pwb[h], 0.f);
        if (adja && !adjb) {
#pragma unroll
            for (int h = 0; h < 4; ++h)
                lb += fmaxf(pwb[h] + CMARG - pw[h], 0.f);
        }
    }
#pragma unroll
    for (int mask = 1; mask < 64; mask <<= 1) {
        lg += __shfl_xor(lg, mask, 64);
        lb += __shfl_xor(lb, mask, 64);
    }
    if (lane == 0) { slg[wave] = lg; slb[wave] = lb; }
    __syncthreads();
    if (tid == 0) {
        partials[blockIdx.x * 2]     = slg[0] + slg[1] + slg[2] + slg[3];
        partials[blockIdx.x * 2 + 1] = slb[0] + slb[1] + slb[2] + slb[3];
    }

    // ---- phase B: aggregate. thread = (nl2, tt); 16 channels/thread ----
    const int nl2 = tid >> 4;
    const int tt  = tid & 15;
    const int hh  = tt >> 2;            // head of this 16-ch slice
    const int n2  = blockIdx.x * 16 + nl2;
    float acc[16];
#pragma unroll
    for (int k = 0; k < 16; ++k) acc[k] = 0.f;
#pragma unroll 4
    for (int j = 0; j < 16; ++j) {
        const int s2 = s_srcn[nl2][j];
        const float awj = s_a[nl2][j][hh];
        const unsigned short* rp = fsb + (size_t)s2 * HD + tt * 16;
        ushort8v u0 = *(const ushort8v*)(rp);
        ushort8v u1 = *(const ushort8v*)(rp + 8);
#pragma unroll
        for (int k = 0; k < 8; ++k) acc[k]     += awj * bf2f(u0[k]);
#pragma unroll
        for (int k = 0; k < 8; ++k) acc[8 + k] += awj * bf2f(u1[k]);
    }
    float* op = out + (size_t)n2 * HD + tt * 16;
#pragma unroll
    for (int i = 0; i < 4; ++i) {
        f32x4 v;
        v[0] = acc[i * 4]; v[1] = acc[i * 4 + 1]; v[2] = acc[i * 4 + 2]; v[3] = acc[i * 4 + 3];
        *(f32x4*)(op + i * 4) = v;
    }
}

// ---------------------------------------------------------------------------
// K3: reduce partials -> Lg, Lb (fp32 scalars; double accumulation)
// ---------------------------------------------------------------------------
__global__ __launch_bounds__(256) void finalize_kernel(const float* __restrict__ partials,
                                                       float* __restrict__ out) {
    const int tid = threadIdx.x;
    const int lane = tid & 63;
    const int wave = tid >> 6;
    double lg = 0.0, lb = 0.0;
    for (int i = tid; i < LOSS_BLOCKS; i += 256) {
        lg += (double)partials[i * 2];
        lb += (double)partials[i * 2 + 1];
    }
#pragma unroll
    for (int mask = 1; mask < 64; mask <<= 1) {
        lg += __shfl_xor(lg, mask, 64);
        lb += __shfl_xor(lb, mask, 64);
    }
    __shared__ double slg[4], slb[4];
    if (lane == 0) { slg[wave] = lg; slb[wave] = lb; }
    __syncthreads();
    if (tid == 0) {
        const double scale = 1.0 / (double)((size_t)N_NODES * HEADS);
        out[(size_t)N_NODES * HD]     = (float)((slg[0] + slg[1] + slg[2] + slg[3]) * scale);
        out[(size_t)N_NODES * HD + 1] = (float)((slb[0] + slb[1] + slb[2] + slb[3]) * scale);
    }
}

extern "C" void kernel_launch(void* const* d_in, const int* in_sizes, int n_in,
                              void* d_out, int out_size, void* d_ws, size_t ws_size,
                              hipStream_t stream) {
    const float* feat   = (const float*)d_in[0];
    const int*   label  = (const int*)d_in[1];
    const int*   src    = (const int*)d_in[2];
    const int*   perm   = (const int*)d_in[4];
    const float* W      = (const float*)d_in[5];
    const float* attn_l = (const float*)d_in[6];
    const float* attn_r = (const float*)d_in[7];
    float* out = (float*)d_out;   // FP32 output

    const int expect[8] = {8388608, 32768, 524288, 524288, 524288, 65536, 256, 256};
    if (n_in != 8) {
        hipLaunchKernelGGL(badcfg_kernel, dim3(1), dim3(1), 0, stream, out, 60000.f);
        return;
    }
    for (int i = 0; i < 8; ++i) {
        if (in_sizes[i] != expect[i]) {
            hipLaunchKernelGGL(badcfg_kernel, dim3(1), dim3(1), 0, stream, out,
                               65536.f + 256.f * (float)i);
            return;
        }
    }
    if (out_size != N_NODES * HD + 2) {
        hipLaunchKernelGGL(badcfg_kernel, dim3(1), dim3(1), 0, stream, out, 200000.f);
        return;
    }

    char* ws = (char*)d_ws;
    size_t off = 0;
    float* partials = (float*)(ws + off); off += (size_t)LOSS_BLOCKS * 2 * sizeof(float);
    off = (off + 255) & ~(size_t)255;
    short* Wb = (short*)(ws + off); off += (size_t)HD * HD * sizeof(short);
    off = (off + 255) & ~(size_t)255;
    unsigned short* fsb = (unsigned short*)(ws + off); off += (size_t)N_NODES * HD * sizeof(unsigned short);
    float* el = (float*)(ws + off); off += (size_t)N_NODES * HEADS * sizeof(float);
    float* er = (float*)(ws + off); off += (size_t)N_NODES * HEADS * sizeof(float);
    if (off > ws_size) {
        hipLaunchKernelGGL(badcfg_kernel, dim3(1), dim3(1), 0, stream, out, 131072.f);
        return;
    }

    hipLaunchKernelGGL(convw_kernel, dim3(HD * HD / 1024), dim3(256), 0, stream, W, Wb);
    hipLaunchKernelGGL(gemm_kernel, dim3(N_NODES / 64), dim3(256), 0, stream,
                       feat, Wb, attn_l, attn_r, fsb, el, er);
    hipLaunchKernelGGL(fla_kernel, dim3(LOSS_BLOCKS), dim3(256), 0, stream,
                       src, perm, label, el, er, fsb, out, partials);
    hipLaunchKernelGGL(finalize_kernel, dim3(1), dim3(256), 0, stream, partials, out);
}